// Round 1
// 177.557 us; speedup vs baseline: 1.0266x; 1.0266x over previous
//
#include <hip/hip_runtime.h>
#include <hip/hip_fp16.h>

// TriLinear 3D-LUT apply: lut (3,33,33,33) f32, img (4,3,1080,1920) f32
// -> out (4,3,1080,1920) f32.
//
// History:
//  R1: LDS-packed LUT, 97 us — latency-bound, serialized gathers (VGPR=64).
//  R3: ILP restructure + img prefetch + persistent blocks -> kernel < 59 us.
//  R4: prepass-quantized LUT + dwordx4 LDS staging -> total 183.1 us.
//  R5: byte LUT + v_perm pair-decode + pk-f16 lerps -> total 181.7 us (-1.4;
//      VALU halving barely moved time => NOT VALU-bound; latency-bound).
//  R6: 2-deep software pipeline @ BLOCK=512 -> 182.3 us (no change vs R5:
//      pipeline bought with occupancy — 2 waves/SIMD can't hide the residual
//      stalls; R5 had 4 waves/SIMD but no pipeline; both plateau ~58 us).
//  R7 (this): pipeline AND occupancy.
//   - BLOCK=768, __launch_bounds__(768,3): 12 waves/CU = 3 waves/SIMD with
//     the same 2-deep pipeline (VGPR cap 168; 2-deep state ~140 regs).
//     LDS (143.7 KB) still limits to 1 block/CU, so waves/CU scales with
//     block size — this is the only occupancy lever available.
//   - LUT staging via global_load_lds width=16: fire-and-forget DMA into
//     LDS, no VGPR round-trip, ~2x fewer staging instructions; the img
//     prefetches issued before staging complete under the same vmcnt drain.

namespace {
constexpr int D_    = 33;
constexpr int D2_   = D_ * D_;        // 1089
constexpr int LUT_N = D_ * D_ * D_;   // 35937
constexpr int HW    = 1080 * 1920;    // 2073600
constexpr int QPB   = HW / 4;         // 518400 quads per (batch,channel) plane
constexpr int NQUADS = 4 * QPB;       // 2073600
constexpr int BLOCK = 768;
constexpr int GRID  = 256;            // 1 persistent block per CU
constexpr int TSTRIDE = GRID * BLOCK; // 196608 -> ~10.5 iters/thread
}

typedef float v4f  __attribute__((ext_vector_type(4)));
typedef unsigned int v4u __attribute__((ext_vector_type(4)));

__device__ __forceinline__ unsigned int quant3(float r, float g, float b) {
    unsigned int qr = (unsigned int)(fminf(fmaxf(r, 0.f), 1.f) * 255.f + 0.5f);
    unsigned int qg = (unsigned int)(fminf(fmaxf(g, 0.f), 1.f) * 255.f + 0.5f);
    unsigned int qb = (unsigned int)(fminf(fmaxf(b, 0.f), 1.f) * 255.f + 0.5f);
    return qr | (qg << 8) | (qb << 16);
}

// ---- pre-pass: quantize + byte-pack the LUT into d_ws (LUT_N dwords) ----
__global__ __launch_bounds__(256)
void quantize_lut_kernel(const float* __restrict__ lut,
                         unsigned int* __restrict__ packed) {
    int i = blockIdx.x * 256 + threadIdx.x;
    if (i < LUT_N)
        packed[i] = quant3(lut[i], lut[i + LUT_N], lut[i + 2 * LUT_N]);
}

struct Img  { v4f x, y, z; int base; };
struct Frag {
    unsigned int cc[4][8];
    __half2 fxh[2], fyh[2];
    float fz[4];
    int base;
};

__device__ __forceinline__ void loadImg(const float* __restrict__ img, int q,
                                        Img& im) {
    int b  = q / QPB;
    int r4 = q - b * QPB;
    im.base = b * 3 * HW + r4 * 4;
    im.x = __builtin_nontemporal_load((const v4f*)(img + im.base));
    im.y = __builtin_nontemporal_load((const v4f*)(img + im.base + HW));
    im.z = __builtin_nontemporal_load((const v4f*)(img + im.base + 2 * HW));
}

// stage1 (indices/fractions) + issue all 16 LDS gathers for one 4-px quad
__device__ __forceinline__ void makeFrag(const unsigned int* __restrict__ slut,
                                         const Img& im, Frag& f) {
    f.base = im.base;
    float fx[4], fy[4];
    int bidx[4];
#pragma unroll
    for (int j = 0; j < 4; ++j) {
        float px = im.x[j] * 32.f;
        float py = im.y[j] * 32.f;
        float pz = im.z[j] * 32.f;
        int ix = (int)px, iy = (int)py, iz = (int)pz;
        fx[j]   = px - (float)ix;
        fy[j]   = py - (float)iy;
        f.fz[j] = pz - (float)iz;
        bidx[j] = iz * D2_ + iy * D_ + ix;
    }
#pragma unroll
    for (int j = 0; j < 4; ++j) {
        int b0 = bidx[j];
        int b1 = b0 + D2_;
        f.cc[j][0] = slut[b0];        f.cc[j][1] = slut[b0 + 1];
        f.cc[j][2] = slut[b0 + D_];   f.cc[j][3] = slut[b0 + D_ + 1];
        f.cc[j][4] = slut[b1];        f.cc[j][5] = slut[b1 + 1];
        f.cc[j][6] = slut[b1 + D_];   f.cc[j][7] = slut[b1 + D_ + 1];
    }
    f.fxh[0] = __floats2half2_rn(fx[0], fx[1]);
    f.fxh[1] = __floats2half2_rn(fx[2], fx[3]);
    f.fyh[0] = __floats2half2_rn(fy[0], fy[1]);
    f.fyh[1] = __floats2half2_rn(fy[2], fy[3]);
}

__device__ __forceinline__ __half2 lerp2(__half2 lo, __half2 hi, __half2 fr) {
    return __hfma2(fr, __hsub2(hi, lo), lo);
}

// pk-f16 blend of one 4-px quad + nontemporal store
__device__ __forceinline__ void blendStore(const Frag& f,
                                           float* __restrict__ out) {
    float outv[3][4];
#pragma unroll
    for (int p = 0; p < 2; ++p) {
        const int j0 = 2 * p, j1 = 2 * p + 1;
        __half2 fhx = f.fxh[p];
        __half2 fhy = f.fyh[p];
        const float fz0 = f.fz[j0], fz1 = f.fz[j1];
#pragma unroll
        for (int c = 0; c < 3; ++c) {
            // dst byte0 = cc[j0] byte c (sel 4+c), byte1 = 0 (sel 0x0C),
            // dst byte2 = cc[j1] byte c (sel c),   byte3 = 0 (sel 0x0C)
            const unsigned int sel = 0x0C000C04u | ((unsigned)c << 16) | (unsigned)c;
            __half2 h[8];
#pragma unroll
            for (int k = 0; k < 8; ++k) {
                union { unsigned int u; __half2 h2; } t;
                t.u = __builtin_amdgcn_perm(f.cc[j0][k], f.cc[j1][k], sel) | 0x5C005C00u;
                h[k] = t.h2;   // {256 + n_j0/4, 256 + n_j1/4} exactly in f16
            }
            __half2 x00 = lerp2(h[0], h[1], fhx);
            __half2 x01 = lerp2(h[2], h[3], fhx);
            __half2 x10 = lerp2(h[4], h[5], fhx);
            __half2 x11 = lerp2(h[6], h[7], fhx);
            __half2 y0  = lerp2(x00, x01, fhy);
            __half2 y1  = lerp2(x10, x11, fhy);
            float y0a = __low2float(y0), y0b = __high2float(y0);
            float y1a = __low2float(y1), y1b = __high2float(y1);
            float za = fmaf(fz0, y1a - y0a, y0a);
            float zb = fmaf(fz1, y1b - y0b, y0b);
            outv[c][j0] = fmaf(za, 4.0f / 255.0f, -1024.0f / 255.0f);
            outv[c][j1] = fmaf(zb, 4.0f / 255.0f, -1024.0f / 255.0f);
        }
    }
    v4f ro = {outv[0][0], outv[0][1], outv[0][2], outv[0][3]};
    v4f go = {outv[1][0], outv[1][1], outv[1][2], outv[1][3]};
    v4f bo = {outv[2][0], outv[2][1], outv[2][2], outv[2][3]};
    __builtin_nontemporal_store(ro, (v4f*)(out + f.base));
    __builtin_nontemporal_store(go, (v4f*)(out + f.base + HW));
    __builtin_nontemporal_store(bo, (v4f*)(out + f.base + 2 * HW));
}

template <bool PACKED>
__global__ __launch_bounds__(BLOCK, 3)
void trilut_kernel(const float* __restrict__ lut,
                   const unsigned int* __restrict__ packed,
                   const float* __restrict__ img,
                   float* __restrict__ out) {
    __shared__ unsigned int slut[LUT_N];   // 143748 B -> 1 block/CU, 12 waves

    Img  im0, im1;
    Frag fg0, fg1;

    // prologue: img loads for iter 0 and 1 issued BEFORE LUT staging so their
    // HBM latency hides under the staging DMA + barrier drain.
    int q0 = blockIdx.x * BLOCK + threadIdx.x;   // < 196608 < NQUADS always
    loadImg(img, q0, im0);
    int q1 = q0 + TSTRIDE;
    bool v1 = q1 < NQUADS;
    if (v1) loadImg(img, q1, im1);

    if (PACKED) {
        // global -> LDS DMA, 16B per lane per issue; destination is linear
        // (wave-uniform base + lane*16), which matches this layout exactly.
        constexpr int NCH = LUT_N / 4;     // 8984 16B chunks + 1 tail dword
        const int lane = threadIdx.x & 63;
        for (int c = threadIdx.x; c < NCH; c += BLOCK) {
            const unsigned int* gsrc = packed + c * 4;
            unsigned int* ldst = slut + (c - lane) * 4;   // wave-uniform base
            __builtin_amdgcn_global_load_lds(
                (const __attribute__((address_space(1))) unsigned int*)gsrc,
                (__attribute__((address_space(3))) unsigned int*)ldst,
                16, 0, 0);
        }
        if (threadIdx.x == 0) slut[LUT_N - 1] = packed[LUT_N - 1];
    } else {
        for (int i = threadIdx.x; i < LUT_N; i += BLOCK)
            slut[i] = quant3(lut[i], lut[i + LUT_N], lut[i + 2 * LUT_N]);
    }
    __syncthreads();   // drains vmcnt(0): staging DMA + im0/im1 all complete

    makeFrag(slut, im0, fg0);              // gathers for iter 0 in flight

    // steady state at body top (parity s): fg[s] gathered, im[s^1] holds
    // img for the next iter, load target im[s] is free.
    while (true) {
        {   // s = 0: blend fg0; produce fg1 from im1; load n+2 -> im0
            int q2 = q1 + TSTRIDE; bool v2 = q2 < NQUADS;
            if (v2) loadImg(img, q2, im0);
            if (v1) makeFrag(slut, im1, fg1);
            blendStore(fg0, out);
            if (!v1) return;
            q1 = q2; v1 = v2;
        }
        {   // s = 1: blend fg1; produce fg0 from im0; load n+2 -> im1
            int q2 = q1 + TSTRIDE; bool v2 = q2 < NQUADS;
            if (v2) loadImg(img, q2, im1);
            if (v1) makeFrag(slut, im0, fg0);
            blendStore(fg1, out);
            if (!v1) return;
            q1 = q2; v1 = v2;
        }
    }
}

extern "C" void kernel_launch(void* const* d_in, const int* in_sizes, int n_in,
                              void* d_out, int out_size, void* d_ws, size_t ws_size,
                              hipStream_t stream) {
    const float* lut = (const float*)d_in[0];
    const float* img = (const float*)d_in[1];
    float* out = (float*)d_out;

    if (ws_size >= (size_t)LUT_N * sizeof(unsigned int)) {
        unsigned int* packed = (unsigned int*)d_ws;
        quantize_lut_kernel<<<(LUT_N + 255) / 256, 256, 0, stream>>>(lut, packed);
        trilut_kernel<true><<<GRID, BLOCK, 0, stream>>>(lut, packed, img, out);
    } else {
        trilut_kernel<false><<<GRID, BLOCK, 0, stream>>>(lut, nullptr, img, out);
    }
}